// Round 1
// baseline (1783.663 us; speedup 1.0000x reference)
//
#include <hip/hip_runtime.h>
#include <hip/hip_bf16.h>

#define FEAT_DIM 768
#define CAPACITY 2048
#define VEC_PER_ROW (FEAT_DIM / 4)   // 192 float4 per row

// One block (192 threads = 3 waves) per sample. Each thread moves one float4.
// Row = 3072 contiguous bytes, 128B-aligned -> fully coalesced 16B/lane loads.
__global__ __launch_bounds__(VEC_PER_ROW) void gather_rows_kernel(
        const float4* __restrict__ bank,
        const int*    __restrict__ center_ids,
        const int*    __restrict__ rand_idx,
        float4*       __restrict__ out) {
    const int s = blockIdx.x;
    const int c = center_ids[s];   // wave-uniform scalar load (broadcast)
    const int r = rand_idx[s];
    // 64-bit offsets: bank spans 1.6 GB of float4s (402M float4 elements)
    const long long src_off = ((long long)c * CAPACITY + r) * (long long)VEC_PER_ROW;
    const long long dst_off = (long long)s * (long long)VEC_PER_ROW;
    out[dst_off + threadIdx.x] = bank[src_off + threadIdx.x];
}

extern "C" void kernel_launch(void* const* d_in, const int* in_sizes, int n_in,
                              void* d_out, int out_size, void* d_ws, size_t ws_size,
                              hipStream_t stream) {
    const float4* bank       = (const float4*)d_in[0];
    const int*    center_ids = (const int*)d_in[1];
    const int*    rand_idx   = (const int*)d_in[2];
    float4*       out        = (float4*)d_out;

    const int batch = in_sizes[1];   // 65536 samples

    gather_rows_kernel<<<batch, VEC_PER_ROW, 0, stream>>>(bank, center_ids, rand_idx, out);
}